// Round 4
// baseline (327.538 us; speedup 1.0000x reference)
//
#include <hip/hip_runtime.h>
#include <math.h>

#define BB 8
#define SS 2048
#define EE 1024
#define HH 64
#define MM (BB * SS)   // 16384 rows

typedef unsigned short u16;
typedef __attribute__((ext_vector_type(8))) short short8;   // 8 x bf16
typedef __attribute__((ext_vector_type(4))) float floatx4;  // mfma C/D

__device__ __forceinline__ u16 f2bf(float f) {
    union { float f; unsigned u; } a; a.f = f;
    unsigned r = a.u + 0x7fffu + ((a.u >> 16) & 1u);   // RNE
    return (u16)(r >> 16);
}

// Split two fp32 into packed bf16 hi (truncated) and bf16 lo (residual, truncated).
// hi+lo reproduces fp32 to ~2^-16 relative.
__device__ __forceinline__ void split2(float f0, float f1, unsigned& hp, unsigned& lp) {
    union { float f; unsigned u; } a0, a1, h0, h1, l0, l1;
    a0.f = f0; a1.f = f1;
    h0.u = a0.u & 0xffff0000u;
    h1.u = a1.u & 0xffff0000u;
    l0.f = f0 - h0.f;
    l1.f = f1 - h1.f;
    hp = __builtin_amdgcn_perm(a1.u, a0.u, 0x07060302u);  // [hi16(f1)|hi16(f0)]
    lp = __builtin_amdgcn_perm(l1.u, l0.u, 0x07060302u);
}

// Async global->LDS, 16B per lane. lds base is wave-uniform; HW adds lane*16.
__device__ __forceinline__ void async_copy16(const u16* g, u16* l) {
    __builtin_amdgcn_global_load_lds(
        (const __attribute__((address_space(1))) unsigned*)g,
        (__attribute__((address_space(3))) unsigned*)l, 16, 0, 0);
}

// ---------------------------------------------------------------------------
// W pre-pack: fp32 W[1024][64] -> bf16 hi/lo fragments in exact MFMA B-frag
// order. Fragment f = t*8 + ks*4 + nt (t = 64-k chunk, ks = 32-k step,
// nt = 16-col tile). For lane l (n = l&15, g = l>>4) the fragment is the 8
// bf16 of W[t*64+ks*32+g*8 .. +7][nt*16+n].
// Layout (u16): Wp[matrix][ (f*2+hl)*512 + lane*8 ]  -> 256 KB per matrix.
// Wq (which==0) is pre-scaled by 0.125 (exact pow2 -> bit-identical flash
// scores), so flash_mfma needs no S scaling.
// ---------------------------------------------------------------------------
#define WP_MAT 131072   // u16 per matrix (128 frags * 2 hl * 512 shorts)

__global__ __launch_bounds__(512) void pack_w(
    const float* __restrict__ W0, const float* __restrict__ W1, const float* __restrict__ W2,
    u16* __restrict__ Wp)
{
    const int which = blockIdx.y;
    const float* __restrict__ W = (which == 0) ? W0 : (which == 1) ? W1 : W2;
    const float scale = (which == 0) ? 0.125f : 1.0f;   // exact pow2
    const int t    = blockIdx.x;           // k-chunk 0..15
    const int tid  = threadIdx.x;          // 0..511
    const int ks   = tid >> 8;
    const int nt   = (tid >> 6) & 3;
    const int lane = tid & 63;
    const int n    = lane & 15;
    const int g    = lane >> 4;

    const int k0 = t * 64 + ks * 32 + g * 8;
    const int c  = nt * 16 + n;

    float e[8];
    #pragma unroll
    for (int j = 0; j < 8; ++j) e[j] = W[(size_t)(k0 + j) * HH + c] * scale;

    unsigned hp[4], lp[4];
    #pragma unroll
    for (int i = 0; i < 4; ++i) split2(e[2 * i], e[2 * i + 1], hp[i], lp[i]);

    u16* dst = Wp + (size_t)which * WP_MAT
                  + ((size_t)(t * 8 + ks * 4 + nt) * 2) * 512 + lane * 8;
    *(uint4*)dst         = (uint4){hp[0], hp[1], hp[2], hp[3]};
    *(uint4*)(dst + 512) = (uint4){lp[0], lp[1], lp[2], lp[3]};
}

// ---------------------------------------------------------------------------
// Projection GEMM via bf16 MFMA + hi/lo compensation (3 passes).
// out[M x 64] = A[M x 1024] @ W[1024 x 64] + b.
// v5: W chunks (16 KB, fragment-ordered, pre-split by pack_w) staged into
//     double-buffered LDS via global_load_lds (pure coalesced copy: no
//     split2, no transpose, no bank conflicts). Inner loop reads fragments
//     with contiguous-1KB ds_read_b128 (conflict-free) -> no global latency
//     on the MFMA path. A per-lane direct global, 2-chunk prefetch ring.
//     Full K per wave (no split-K). Block 256 = 4 waves, wave w = rows
//     [w*16, w*16+16). Grid (256, 3) = 768 blocks = 3 blocks/CU.
// ---------------------------------------------------------------------------
#define PCH 16   // 64-k chunks

__global__ __launch_bounds__(256) void proj_mfma(
    const float* __restrict__ A0, const float* __restrict__ A1, const float* __restrict__ A2,
    const u16* __restrict__ Wp,
    const float* __restrict__ b0, const float* __restrict__ b1, const float* __restrict__ b2,
    u16* __restrict__ o0, u16* __restrict__ o1, u16* __restrict__ o2)
{
    const int which = blockIdx.y;
    const float* __restrict__ A    = (which == 0) ? A0 : (which == 1) ? A1 : A2;
    const float* __restrict__ bias = (which == 0) ? b0 : (which == 1) ? b1 : b2;
    u16* __restrict__ out          = (which == 0) ? o0 : (which == 1) ? o1 : o2;
    const float bscale = (which == 0) ? 0.125f : 1.0f;

    __shared__ __align__(16) u16 Wb[2][8192];   // 16 KB per buffer

    const int tid  = threadIdx.x;
    const int lane = tid & 63;
    const int wave = tid >> 6;
    const int n    = lane & 15;
    const int g    = lane >> 4;
    const int row0 = blockIdx.x * 64;

    // A fragment source: row (row0 + wave*16 + n), 8 contiguous floats at g*8
    const float* __restrict__ ap = A + (size_t)(row0 + wave * 16 + n) * EE + g * 8;
    // W packed source for this matrix
    const u16* __restrict__ wpb = Wp + (size_t)which * WP_MAT;

    floatx4 acc[4];
    #pragma unroll
    for (int nt = 0; nt < 4; ++nt) acc[nt] = (floatx4){0.f, 0.f, 0.f, 0.f};

    // ---- prologue: A chunks 0,1 -> regs; W chunk 0 -> LDS buf 0 -----------
    float4 av[2][4];   // [slot][ks*2 + half]: ks*32 + g*8 (+4)
    #pragma unroll
    for (int s = 0; s < 2; ++s) {
        const float* p = ap + s * 64;
        av[s][0] = *(const float4*)(p + 0);
        av[s][1] = *(const float4*)(p + 4);
        av[s][2] = *(const float4*)(p + 32);
        av[s][3] = *(const float4*)(p + 36);
    }
    {
        const u16* src = wpb + wave * 2048 + lane * 8;
        #pragma unroll
        for (int i = 0; i < 4; ++i)
            async_copy16(src + i * 512, &Wb[0][wave * 2048 + i * 512]);
    }
    __syncthreads();

    for (int t = 0; t < PCH; ++t) {
        const int cur = t & 1;

        // ---- issue next W chunk's stage (hides under the MFMAs below) ----
        if (t + 1 < PCH) {
            const u16* src = wpb + (size_t)(t + 1) * 8192 + wave * 2048 + lane * 8;
            u16* dst = &Wb[cur ^ 1][wave * 2048];
            #pragma unroll
            for (int i = 0; i < 4; ++i)
                async_copy16(src + i * 512, dst + i * 512);
        }

        // ---- split current A chunk to bf16 hi/lo (frees av[cur]) ---------
        short8 ah[2], al[2];
        #pragma unroll
        for (int ks = 0; ks < 2; ++ks) {
            unsigned hp0, lp0, hp1, lp1, hp2, lp2, hp3, lp3;
            split2(av[cur][ks * 2].x,     av[cur][ks * 2].y,     hp0, lp0);
            split2(av[cur][ks * 2].z,     av[cur][ks * 2].w,     hp1, lp1);
            split2(av[cur][ks * 2 + 1].x, av[cur][ks * 2 + 1].y, hp2, lp2);
            split2(av[cur][ks * 2 + 1].z, av[cur][ks * 2 + 1].w, hp3, lp3);
            union { uint4 u; short8 s; } ch, cl;
            ch.u = (uint4){hp0, hp1, hp2, hp3};
            cl.u = (uint4){lp0, lp1, lp2, lp3};
            ah[ks] = ch.s; al[ks] = cl.s;
        }

        // ---- prefetch A chunk t+2 into the freed slot --------------------
        if (t + 2 < PCH) {
            const float* p = ap + (t + 2) * 64;
            av[cur][0] = *(const float4*)(p + 0);
            av[cur][1] = *(const float4*)(p + 4);
            av[cur][2] = *(const float4*)(p + 32);
            av[cur][3] = *(const float4*)(p + 36);
        }

        // ---- W fragments from LDS (contiguous b128, conflict-free) + MFMA
        #pragma unroll
        for (int ks = 0; ks < 2; ++ks)
            #pragma unroll
            for (int nt = 0; nt < 4; ++nt) {
                const int f = ks * 4 + nt;
                const short8 whf = *(const short8*)&Wb[cur][f * 1024 + lane * 8];
                const short8 wlf = *(const short8*)&Wb[cur][f * 1024 + 512 + lane * 8];
                acc[nt] = __builtin_amdgcn_mfma_f32_16x16x32_bf16(ah[ks], whf, acc[nt], 0, 0, 0);
                acc[nt] = __builtin_amdgcn_mfma_f32_16x16x32_bf16(al[ks], whf, acc[nt], 0, 0, 0);
                acc[nt] = __builtin_amdgcn_mfma_f32_16x16x32_bf16(ah[ks], wlf, acc[nt], 0, 0, 0);
            }

        __syncthreads();   // next buffer staged; everyone done with cur
    }

    // ---- epilogue: bias + bf16 store -------------------------------------
    #pragma unroll
    for (int nt = 0; nt < 4; ++nt) {
        const float bv = bias[nt * 16 + n] * bscale;
        #pragma unroll
        for (int r = 0; r < 4; ++r) {
            const int row = row0 + wave * 16 + g * 4 + r;
            out[(size_t)row * HH + nt * 16 + n] = f2bf(acc[nt][r] + bv);
        }
    }
}

// ---------------------------------------------------------------------------
// MFMA flash attention, double-buffered 64-key tiles, 1 barrier/iter.
// Block 256 thr = 4 waves: wq = wave&1 (16-q tile), ks = wave>>1 (32-key half).
// Grid (64, 8). Next tile loaded to regs before compute, written after.
// NOTE: qp is pre-scaled by 0.125 (folded into Wq/bq), so no S scaling here.
// ---------------------------------------------------------------------------
__global__ __launch_bounds__(256) void flash_mfma(
    const u16* __restrict__ qp, const u16* __restrict__ kp,
    const u16* __restrict__ vp, float* __restrict__ out)
{
    __shared__ __align__(16) u16 Ks[2][64 * 64];   // row j: 8 chunks, chunk cs at cs^(j&7)
    __shared__ __align__(16) u16 Vt[2][64 * 64];   // row h: 8 j-chunks, chunk cj at cj^(h&7)
    __shared__ __align__(16) u16 Pw[4][16 * 72];

    const int b    = blockIdx.y;
    const int q0   = blockIdx.x * 32;
    const int tid  = threadIdx.x;
    const int lane = tid & 63;
    const int wave = tid >> 6;
    const int wq   = wave & 1;
    const int ks   = wave >> 1;
    const int n    = lane & 15;
    const int g    = lane >> 4;

    const u16* qrow = qp + ((size_t)b * SS + q0 + wq * 16 + n) * HH;
    const short8 qa0 = *(const short8*)(qrow + g * 8);
    const short8 qa1 = *(const short8*)(qrow + 32 + g * 8);

    floatx4 Oa[4];
    #pragma unroll
    for (int ht = 0; ht < 4; ++ht) Oa[ht] = (floatx4){0.f, 0.f, 0.f, 0.f};
    float m_i[4], l_i[4];
    #pragma unroll
    for (int r = 0; r < 4; ++r) { m_i[r] = -1e30f; l_i[r] = 0.f; }

    const u16* kb = kp + (size_t)b * SS * HH;
    const u16* vb = vp + (size_t)b * SS * HH;

    // staging indices (tid-only)
    const int jK0 = tid >> 3, jK1 = 32 + (tid >> 3), cs = tid & 7;
    const int jV  = (tid & 15) * 4, hV = (tid >> 4) * 4;

    short8  kr0, kr1;
    ushort4 vr0, vr1, vr2, vr3;

    // ---- prologue: stage tile 0 into buf 0 --------------------------------
    kr0 = *(const short8*)(kb + (size_t)jK0 * HH + cs * 8);
    kr1 = *(const short8*)(kb + (size_t)jK1 * HH + cs * 8);
    vr0 = *(const ushort4*)(vb + (size_t)(jV + 0) * HH + hV);
    vr1 = *(const ushort4*)(vb + (size_t)(jV + 1) * HH + hV);
    vr2 = *(const ushort4*)(vb + (size_t)(jV + 2) * HH + hV);
    vr3 = *(const ushort4*)(vb + (size_t)(jV + 3) * HH + hV);
    {
        *(short8*)&Ks[0][jK0 * 64 + ((cs ^ (jK0 & 7)) << 3)] = kr0;
        *(short8*)&Ks[0][jK1 * 64 + ((cs ^ (jK1 & 7)) << 3)] = kr1;
        const u16* a0 = (const u16*)&vr0; const u16* a1 = (const u16*)&vr1;
        const u16* a2 = (const u16*)&vr2; const u16* a3 = (const u16*)&vr3;
        #pragma unroll
        for (int i = 0; i < 4; ++i) {
            const int h = hV + i;
            ushort4 w; w.x = a0[i]; w.y = a1[i]; w.z = a2[i]; w.w = a3[i];
            *(ushort4*)((char*)&Vt[0][0] + h * 128 + (((jV >> 3) ^ (h & 7)) << 4) + ((jV & 4) << 1)) = w;
        }
    }
    __syncthreads();

    for (int t = 0; t < SS / 64; ++t) {
        const int cur = t & 1;

        // ---- issue next tile's global loads (latency hides under compute) --
        if (t + 1 < SS / 64) {
            const size_t kt = (size_t)(t + 1) * 64;
            kr0 = *(const short8*)(kb + (kt + jK0) * HH + cs * 8);
            kr1 = *(const short8*)(kb + (kt + jK1) * HH + cs * 8);
            vr0 = *(const ushort4*)(vb + (kt + jV + 0) * HH + hV);
            vr1 = *(const ushort4*)(vb + (kt + jV + 1) * HH + hV);
            vr2 = *(const ushort4*)(vb + (kt + jV + 2) * HH + hV);
            vr3 = *(const ushort4*)(vb + (kt + jV + 3) * HH + hV);
        }

        // ---- QK^T: S[16 q][32 keys] (my half) ------------------------------
        floatx4 S[2];
        #pragma unroll
        for (int nt = 0; nt < 2; ++nt) {
            const int j = ks * 32 + nt * 16 + n;
            const short8 kf0 = *(const short8*)&Ks[cur][j * 64 + (((0 + g) ^ (j & 7)) << 3)];
            const short8 kf1 = *(const short8*)&Ks[cur][j * 64 + (((4 + g) ^ (j & 7)) << 3)];
            floatx4 a = (floatx4){0.f, 0.f, 0.f, 0.f};
            a = __builtin_amdgcn_mfma_f32_16x16x32_bf16(qa0, kf0, a, 0, 0, 0);
            a = __builtin_amdgcn_mfma_f32_16x16x32_bf16(qa1, kf1, a, 0, 0, 0);
            S[nt] = a;
        }

        // ---- online softmax ------------------------------------------------
        float mx[4];
        #pragma unroll
        for (int r = 0; r < 4; ++r) mx[r] = -1e30f;
        #pragma unroll
        for (int nt = 0; nt < 2; ++nt)
            #pragma unroll
            for (int r = 0; r < 4; ++r)
                mx[r] = fmaxf(mx[r], S[nt][r]);
        #pragma unroll
        for (int off = 8; off >= 1; off >>= 1)
            #pragma unroll
            for (int r = 0; r < 4; ++r)
                mx[r] = fmaxf(mx[r], __shfl_xor(mx[r], off, 64));

        float alpha[4], ps[4];
        #pragma unroll
        for (int r = 0; r < 4; ++r) {
            const float Mn = fmaxf(m_i[r], mx[r]);
            alpha[r] = __expf(m_i[r] - Mn);
            m_i[r]   = Mn;
            ps[r]    = 0.f;
        }
        float p[2][4];
        #pragma unroll
        for (int nt = 0; nt < 2; ++nt)
            #pragma unroll
            for (int r = 0; r < 4; ++r) {
                p[nt][r] = __expf(S[nt][r] - m_i[r]);
                ps[r] += p[nt][r];
            }
        #pragma unroll
        for (int off = 8; off >= 1; off >>= 1)
            #pragma unroll
            for (int r = 0; r < 4; ++r)
                ps[r] += __shfl_xor(ps[r], off, 64);
        #pragma unroll
        for (int r = 0; r < 4; ++r) l_i[r] = l_i[r] * alpha[r] + ps[r];
        #pragma unroll
        for (int ht = 0; ht < 4; ++ht)
            #pragma unroll
            for (int r = 0; r < 4; ++r) Oa[ht][r] *= alpha[r];

        // ---- P: C-layout -> LDS -> A-layout (per-wave, no barrier needed) --
        #pragma unroll
        for (int nt = 0; nt < 2; ++nt)
            #pragma unroll
            for (int r = 0; r < 4; ++r)
                Pw[wave][(g * 4 + r) * 72 + nt * 16 + n] = f2bf(p[nt][r]);
        const short8 pa = *(const short8*)&Pw[wave][n * 72 + g * 8];

        // ---- PV: O[16 q][64 h] += P[16 x 32] @ V[32 x 64] ------------------
        #pragma unroll
        for (int ht = 0; ht < 4; ++ht) {
            const int h = ht * 16 + n;
            const short8 vf = *(const short8*)((const char*)&Vt[cur][0] + h * 128 +
                                               ((((ks << 2) + g) ^ (h & 7)) << 4));
            Oa[ht] = __builtin_amdgcn_mfma_f32_16x16x32_bf16(pa, vf, Oa[ht], 0, 0, 0);
        }

        // ---- write next tile into the other buffer -------------------------
        if (t + 1 < SS / 64) {
            const int nx = cur ^ 1;
            *(short8*)&Ks[nx][jK0 * 64 + ((cs ^ (jK0 & 7)) << 3)] = kr0;
            *(short8*)&Ks[nx][jK1 * 64 + ((cs ^ (jK1 & 7)) << 3)] = kr1;
            const u16* a0 = (const u16*)&vr0; const u16* a1 = (const u16*)&vr1;
            const u16* a2 = (const u16*)&vr2; const u16* a3 = (const u16*)&vr3;
            #pragma unroll
            for (int i = 0; i < 4; ++i) {
                const int h = hV + i;
                ushort4 w; w.x = a0[i]; w.y = a1[i]; w.z = a2[i]; w.w = a3[i];
                *(ushort4*)((char*)&Vt[nx][0] + h * 128 + (((jV >> 3) ^ (h & 7)) << 4) + ((jV & 4) << 1)) = w;
            }
        }
        __syncthreads();
    }

    // ---- combine the two key-splits via LDS (reuse Ks) ----------------------
    float* Cb = (float*)&Ks[0][0];          // [wq][16][68]
    float* Cm = Cb + 2 * 16 * 68;           // [wq][16]
    float* Cl = Cm + 32;
    if (ks == 1) {
        #pragma unroll
        for (int ht = 0; ht < 4; ++ht)
            #pragma unroll
            for (int r = 0; r < 4; ++r)
                Cb[(wq * 16 + g * 4 + r) * 68 + ht * 16 + n] = Oa[ht][r];
        if (n == 0)
            #pragma unroll
            for (int r = 0; r < 4; ++r) {
                Cm[wq * 16 + g * 4 + r] = m_i[r];
                Cl[wq * 16 + g * 4 + r] = l_i[r];
            }
    }
    __syncthreads();
    if (ks == 0) {
        float a0v[4], a1v[4], linv[4];
        #pragma unroll
        for (int r = 0; r < 4; ++r) {
            const int m = g * 4 + r;
            const float m1 = Cm[wq * 16 + m], l1 = Cl[wq * 16 + m];
            const float M  = fmaxf(m_i[r], m1);
            const float e0 = __expf(m_i[r] - M), e1 = __expf(m1 - M);
            a0v[r] = e0; a1v[r] = e1;
            linv[r] = 1.f / (l_i[r] * e0 + l1 * e1);
        }
        #pragma unroll
        for (int ht = 0; ht < 4; ++ht)
            #pragma unroll
            for (int r = 0; r < 4; ++r) {
                const float o1 = Cb[(wq * 16 + g * 4 + r) * 68 + ht * 16 + n];
                const float v  = (Oa[ht][r] * a0v[r] + o1 * a1v[r]) * linv[r];
                out[((size_t)b * SS + q0 + wq * 16 + g * 4 + r) * HH + ht * 16 + n] = v;
            }
    }
}

// ---------------------------------------------------------------------------
extern "C" void kernel_launch(void* const* d_in, const int* in_sizes, int n_in,
                              void* d_out, int out_size, void* d_ws, size_t ws_size,
                              hipStream_t stream) {
    const float* query = (const float*)d_in[0];
    const float* key   = (const float*)d_in[1];
    const float* value = (const float*)d_in[2];
    const float* Wq    = (const float*)d_in[3];
    const float* bq    = (const float*)d_in[4];
    const float* Wk    = (const float*)d_in[5];
    const float* bk    = (const float*)d_in[6];
    const float* Wv    = (const float*)d_in[7];
    const float* bv    = (const float*)d_in[8];
    float* out = (float*)d_out;

    u16* qp = (u16*)d_ws;                        // 16384 x 64 bf16 each
    u16* kp = qp + (size_t)MM * HH;
    u16* vp = kp + (size_t)MM * HH;
    u16* Wp = vp + (size_t)MM * HH;              // 3 * 256 KB packed W frags

    dim3 wgrid(EE / 64, 3);
    pack_w<<<wgrid, 512, 0, stream>>>(Wq, Wk, Wv, Wp);

    dim3 pgrid(MM / 64, 3);
    proj_mfma<<<pgrid, 256, 0, stream>>>(query, key, value,
                                         Wp,
                                         bq, bk, bv,
                                         qp, kp, vp);

    dim3 agrid(SS / 32, BB);
    flash_mfma<<<agrid, 256, 0, stream>>>(qp, kp, vp, out);
}

// Round 5
// 266.341 us; speedup vs baseline: 1.2298x; 1.2298x over previous
//
#include <hip/hip_runtime.h>
#include <math.h>

#define BB 8
#define SS 2048
#define EE 1024
#define HH 64
#define MM (BB * SS)   // 16384 rows

typedef unsigned short u16;
typedef __attribute__((ext_vector_type(8))) short short8;   // 8 x bf16
typedef __attribute__((ext_vector_type(4))) float floatx4;  // mfma C/D

__device__ __forceinline__ u16 f2bf(float f) {
    union { float f; unsigned u; } a; a.f = f;
    unsigned r = a.u + 0x7fffu + ((a.u >> 16) & 1u);   // RNE
    return (u16)(r >> 16);
}

// Split two fp32 into packed bf16 hi (truncated) and bf16 lo (residual, truncated).
// hi+lo reproduces fp32 to ~2^-16 relative.
__device__ __forceinline__ void split2(float f0, float f1, unsigned& hp, unsigned& lp) {
    union { float f; unsigned u; } a0, a1, h0, h1, l0, l1;
    a0.f = f0; a1.f = f1;
    h0.u = a0.u & 0xffff0000u;
    h1.u = a1.u & 0xffff0000u;
    l0.f = f0 - h0.f;
    l1.f = f1 - h1.f;
    hp = __builtin_amdgcn_perm(a1.u, a0.u, 0x07060302u);  // [hi16(f1)|hi16(f0)]
    lp = __builtin_amdgcn_perm(l1.u, l0.u, 0x07060302u);
}

// Async global->LDS, 16B per lane. lds base is wave-uniform; HW adds lane*16.
__device__ __forceinline__ void async_copy16(const u16* g, u16* l) {
    __builtin_amdgcn_global_load_lds(
        (const __attribute__((address_space(1))) unsigned*)g,
        (__attribute__((address_space(3))) unsigned*)l, 16, 0, 0);
}

// ---------------------------------------------------------------------------
// W pre-pack: fp32 W[1024][64] -> bf16 hi/lo fragments in exact MFMA B-frag
// order. Fragment f = t*8 + ks*4 + nt (t = 64-k chunk, ks = 32-k step,
// nt = 16-col tile). For lane l (n = l&15, g = l>>4) the fragment is the 8
// bf16 of W[t*64+ks*32+g*8 .. +7][nt*16+n].
// Layout (u16): Wp[matrix][ (f*2+hl)*512 + lane*8 ]  -> 256 KB per matrix.
// Wq (which==0) is pre-scaled by 0.125 (exact pow2 -> bit-identical flash
// scores), so flash_mfma needs no S scaling.
// ---------------------------------------------------------------------------
#define WP_MAT 131072   // u16 per matrix (128 frags * 2 hl * 512 shorts)

__global__ __launch_bounds__(512) void pack_w(
    const float* __restrict__ W0, const float* __restrict__ W1, const float* __restrict__ W2,
    u16* __restrict__ Wp)
{
    const int which = blockIdx.y;
    const float* __restrict__ W = (which == 0) ? W0 : (which == 1) ? W1 : W2;
    const float scale = (which == 0) ? 0.125f : 1.0f;   // exact pow2
    const int t    = blockIdx.x;           // k-chunk 0..15
    const int tid  = threadIdx.x;          // 0..511
    const int ks   = tid >> 8;
    const int nt   = (tid >> 6) & 3;
    const int lane = tid & 63;
    const int n    = lane & 15;
    const int g    = lane >> 4;

    const int k0 = t * 64 + ks * 32 + g * 8;
    const int c  = nt * 16 + n;

    float e[8];
    #pragma unroll
    for (int j = 0; j < 8; ++j) e[j] = W[(size_t)(k0 + j) * HH + c] * scale;

    unsigned hp[4], lp[4];
    #pragma unroll
    for (int i = 0; i < 4; ++i) split2(e[2 * i], e[2 * i + 1], hp[i], lp[i]);

    u16* dst = Wp + (size_t)which * WP_MAT
                  + ((size_t)(t * 8 + ks * 4 + nt) * 2) * 512 + lane * 8;
    *(uint4*)dst         = (uint4){hp[0], hp[1], hp[2], hp[3]};
    *(uint4*)(dst + 512) = (uint4){lp[0], lp[1], lp[2], lp[3]};
}

// ---------------------------------------------------------------------------
// Projection GEMM via bf16 MFMA + hi/lo compensation (3 passes).
// out[M x 64] = A[M x 1024] @ W[1024 x 64] + b.
// v6 = v5 with GUARANTEED static register indexing (rule #20): the chunk
//     loop is hand-unrolled x2 with named A slots avA/avB and literal LDS
//     buffer indices, so nothing spills to scratch (R4's 200 MB WRITE_SIZE
//     regression). W chunks (16 KB, fragment-ordered, pre-split by pack_w)
//     staged into double-buffered LDS via global_load_lds; inner loop reads
//     fragments with contiguous-1KB ds_read_b128 (conflict-free). A per-lane
//     direct global, 2-chunk prefetch ring. Block 256 = 4 waves, wave w =
//     rows [w*16, w*16+16). Grid (256, 3) = 768 blocks = 3 blocks/CU.
// ---------------------------------------------------------------------------
#define PCH 16   // 64-k chunks

#define LOAD_A(AV, T)                                   \
    {                                                   \
        const float* p_ = ap + (T) * 64;                \
        AV[0] = *(const float4*)(p_ + 0);               \
        AV[1] = *(const float4*)(p_ + 4);               \
        AV[2] = *(const float4*)(p_ + 32);              \
        AV[3] = *(const float4*)(p_ + 36);              \
    }

// One 64-k chunk: stage W chunk TSTAGE into Wb[CURBUF^1], split AV (in regs),
// prefetch A chunk TPREF into AV, MFMA from Wb[CURBUF], barrier.
#define PROJ_CHUNK(AV, CURBUF, TSTAGE, TPREF)                                      \
    {                                                                              \
        if ((TSTAGE) < PCH) {                                                      \
            const u16* src_ = wpb + (size_t)(TSTAGE) * 8192 + wave * 2048 + lane * 8; \
            u16* dst_ = &Wb[(CURBUF) ^ 1][wave * 2048];                            \
            async_copy16(src_ + 0 * 512, dst_ + 0 * 512);                          \
            async_copy16(src_ + 1 * 512, dst_ + 1 * 512);                          \
            async_copy16(src_ + 2 * 512, dst_ + 2 * 512);                          \
            async_copy16(src_ + 3 * 512, dst_ + 3 * 512);                          \
        }                                                                          \
        short8 ah0, ah1, al0, al1;                                                 \
        {                                                                          \
            unsigned hp0, lp0, hp1, lp1, hp2, lp2, hp3, lp3;                       \
            split2(AV[0].x, AV[0].y, hp0, lp0);                                    \
            split2(AV[0].z, AV[0].w, hp1, lp1);                                    \
            split2(AV[1].x, AV[1].y, hp2, lp2);                                    \
            split2(AV[1].z, AV[1].w, hp3, lp3);                                    \
            union { uint4 u; short8 s; } ch_, cl_;                                 \
            ch_.u = (uint4){hp0, hp1, hp2, hp3};                                   \
            cl_.u = (uint4){lp0, lp1, lp2, lp3};                                   \
            ah0 = ch_.s; al0 = cl_.s;                                              \
            split2(AV[2].x, AV[2].y, hp0, lp0);                                    \
            split2(AV[2].z, AV[2].w, hp1, lp1);                                    \
            split2(AV[3].x, AV[3].y, hp2, lp2);                                    \
            split2(AV[3].z, AV[3].w, hp3, lp3);                                    \
            ch_.u = (uint4){hp0, hp1, hp2, hp3};                                   \
            cl_.u = (uint4){lp0, lp1, lp2, lp3};                                   \
            ah1 = ch_.s; al1 = cl_.s;                                              \
        }                                                                          \
        if ((TPREF) < PCH) LOAD_A(AV, TPREF);                                      \
        _Pragma("unroll")                                                          \
        for (int nt = 0; nt < 4; ++nt) {                                           \
            const short8 whf = *(const short8*)&Wb[CURBUF][nt * 1024 + lane * 8];  \
            const short8 wlf = *(const short8*)&Wb[CURBUF][nt * 1024 + 512 + lane * 8]; \
            acc[nt] = __builtin_amdgcn_mfma_f32_16x16x32_bf16(ah0, whf, acc[nt], 0, 0, 0); \
            acc[nt] = __builtin_amdgcn_mfma_f32_16x16x32_bf16(al0, whf, acc[nt], 0, 0, 0); \
            acc[nt] = __builtin_amdgcn_mfma_f32_16x16x32_bf16(ah0, wlf, acc[nt], 0, 0, 0); \
        }                                                                          \
        _Pragma("unroll")                                                          \
        for (int nt = 0; nt < 4; ++nt) {                                           \
            const short8 whf = *(const short8*)&Wb[CURBUF][4096 + nt * 1024 + lane * 8]; \
            const short8 wlf = *(const short8*)&Wb[CURBUF][4096 + nt * 1024 + 512 + lane * 8]; \
            acc[nt] = __builtin_amdgcn_mfma_f32_16x16x32_bf16(ah1, whf, acc[nt], 0, 0, 0); \
            acc[nt] = __builtin_amdgcn_mfma_f32_16x16x32_bf16(al1, whf, acc[nt], 0, 0, 0); \
            acc[nt] = __builtin_amdgcn_mfma_f32_16x16x32_bf16(ah1, wlf, acc[nt], 0, 0, 0); \
        }                                                                          \
        __syncthreads();                                                           \
    }

__global__ __launch_bounds__(256) void proj_mfma(
    const float* __restrict__ A0, const float* __restrict__ A1, const float* __restrict__ A2,
    const u16* __restrict__ Wp,
    const float* __restrict__ b0, const float* __restrict__ b1, const float* __restrict__ b2,
    u16* __restrict__ o0, u16* __restrict__ o1, u16* __restrict__ o2)
{
    const int which = blockIdx.y;
    const float* __restrict__ A    = (which == 0) ? A0 : (which == 1) ? A1 : A2;
    const float* __restrict__ bias = (which == 0) ? b0 : (which == 1) ? b1 : b2;
    u16* __restrict__ out          = (which == 0) ? o0 : (which == 1) ? o1 : o2;
    const float bscale = (which == 0) ? 0.125f : 1.0f;

    __shared__ __align__(16) u16 Wb[2][8192];   // 16 KB per buffer

    const int tid  = threadIdx.x;
    const int lane = tid & 63;
    const int wave = tid >> 6;
    const int n    = lane & 15;
    const int g    = lane >> 4;
    const int row0 = blockIdx.x * 64;

    // A fragment source: row (row0 + wave*16 + n), 8 contiguous floats at g*8
    const float* __restrict__ ap = A + (size_t)(row0 + wave * 16 + n) * EE + g * 8;
    // W packed source for this matrix
    const u16* __restrict__ wpb = Wp + (size_t)which * WP_MAT;

    floatx4 acc[4];
    #pragma unroll
    for (int nt = 0; nt < 4; ++nt) acc[nt] = (floatx4){0.f, 0.f, 0.f, 0.f};

    // ---- prologue: A chunks 0,1 -> named reg slots; W chunk 0 -> LDS buf 0
    float4 avA[4], avB[4];   // [ks*2 + half]: ks*32 + g*8 (+4)
    LOAD_A(avA, 0);
    LOAD_A(avB, 1);
    {
        const u16* src = wpb + wave * 2048 + lane * 8;
        u16* dst = &Wb[0][wave * 2048];
        #pragma unroll
        for (int i = 0; i < 4; ++i)
            async_copy16(src + i * 512, dst + i * 512);
    }
    __syncthreads();

    // ---- main loop: hand-unrolled x2, all buffer/slot indices literal -----
    for (int tt = 0; tt < PCH; tt += 2) {
        PROJ_CHUNK(avA, 0, tt + 1, tt + 2);   // compute chunk tt   from Wb[0]
        PROJ_CHUNK(avB, 1, tt + 2, tt + 3);   // compute chunk tt+1 from Wb[1]
    }

    // ---- epilogue: bias + bf16 store -------------------------------------
    #pragma unroll
    for (int nt = 0; nt < 4; ++nt) {
        const float bv = bias[nt * 16 + n] * bscale;
        #pragma unroll
        for (int r = 0; r < 4; ++r) {
            const int row = row0 + wave * 16 + g * 4 + r;
            out[(size_t)row * HH + nt * 16 + n] = f2bf(acc[nt][r] + bv);
        }
    }
}

// ---------------------------------------------------------------------------
// MFMA flash attention, double-buffered 64-key tiles, 1 barrier/iter.
// Block 256 thr = 4 waves: wq = wave&1 (16-q tile), ks = wave>>1 (32-key half).
// Grid (64, 8). Next tile loaded to regs before compute, written after.
// NOTE: qp is pre-scaled by 0.125 (folded into Wq/bq), so no S scaling here.
// ---------------------------------------------------------------------------
__global__ __launch_bounds__(256) void flash_mfma(
    const u16* __restrict__ qp, const u16* __restrict__ kp,
    const u16* __restrict__ vp, float* __restrict__ out)
{
    __shared__ __align__(16) u16 Ks[2][64 * 64];   // row j: 8 chunks, chunk cs at cs^(j&7)
    __shared__ __align__(16) u16 Vt[2][64 * 64];   // row h: 8 j-chunks, chunk cj at cj^(h&7)
    __shared__ __align__(16) u16 Pw[4][16 * 72];

    const int b    = blockIdx.y;
    const int q0   = blockIdx.x * 32;
    const int tid  = threadIdx.x;
    const int lane = tid & 63;
    const int wave = tid >> 6;
    const int wq   = wave & 1;
    const int ks   = wave >> 1;
    const int n    = lane & 15;
    const int g    = lane >> 4;

    const u16* qrow = qp + ((size_t)b * SS + q0 + wq * 16 + n) * HH;
    const short8 qa0 = *(const short8*)(qrow + g * 8);
    const short8 qa1 = *(const short8*)(qrow + 32 + g * 8);

    floatx4 Oa[4];
    #pragma unroll
    for (int ht = 0; ht < 4; ++ht) Oa[ht] = (floatx4){0.f, 0.f, 0.f, 0.f};
    float m_i[4], l_i[4];
    #pragma unroll
    for (int r = 0; r < 4; ++r) { m_i[r] = -1e30f; l_i[r] = 0.f; }

    const u16* kb = kp + (size_t)b * SS * HH;
    const u16* vb = vp + (size_t)b * SS * HH;

    // staging indices (tid-only)
    const int jK0 = tid >> 3, jK1 = 32 + (tid >> 3), cs = tid & 7;
    const int jV  = (tid & 15) * 4, hV = (tid >> 4) * 4;

    short8  kr0, kr1;
    ushort4 vr0, vr1, vr2, vr3;

    // ---- prologue: stage tile 0 into buf 0 --------------------------------
    kr0 = *(const short8*)(kb + (size_t)jK0 * HH + cs * 8);
    kr1 = *(const short8*)(kb + (size_t)jK1 * HH + cs * 8);
    vr0 = *(const ushort4*)(vb + (size_t)(jV + 0) * HH + hV);
    vr1 = *(const ushort4*)(vb + (size_t)(jV + 1) * HH + hV);
    vr2 = *(const ushort4*)(vb + (size_t)(jV + 2) * HH + hV);
    vr3 = *(const ushort4*)(vb + (size_t)(jV + 3) * HH + hV);
    {
        *(short8*)&Ks[0][jK0 * 64 + ((cs ^ (jK0 & 7)) << 3)] = kr0;
        *(short8*)&Ks[0][jK1 * 64 + ((cs ^ (jK1 & 7)) << 3)] = kr1;
        const u16* a0 = (const u16*)&vr0; const u16* a1 = (const u16*)&vr1;
        const u16* a2 = (const u16*)&vr2; const u16* a3 = (const u16*)&vr3;
        #pragma unroll
        for (int i = 0; i < 4; ++i) {
            const int h = hV + i;
            ushort4 w; w.x = a0[i]; w.y = a1[i]; w.z = a2[i]; w.w = a3[i];
            *(ushort4*)((char*)&Vt[0][0] + h * 128 + (((jV >> 3) ^ (h & 7)) << 4) + ((jV & 4) << 1)) = w;
        }
    }
    __syncthreads();

    for (int t = 0; t < SS / 64; ++t) {
        const int cur = t & 1;

        // ---- issue next tile's global loads (latency hides under compute) --
        if (t + 1 < SS / 64) {
            const size_t kt = (size_t)(t + 1) * 64;
            kr0 = *(const short8*)(kb + (kt + jK0) * HH + cs * 8);
            kr1 = *(const short8*)(kb + (kt + jK1) * HH + cs * 8);
            vr0 = *(const ushort4*)(vb + (kt + jV + 0) * HH + hV);
            vr1 = *(const ushort4*)(vb + (kt + jV + 1) * HH + hV);
            vr2 = *(const ushort4*)(vb + (kt + jV + 2) * HH + hV);
            vr3 = *(const ushort4*)(vb + (kt + jV + 3) * HH + hV);
        }

        // ---- QK^T: S[16 q][32 keys] (my half) ------------------------------
        floatx4 S[2];
        #pragma unroll
        for (int nt = 0; nt < 2; ++nt) {
            const int j = ks * 32 + nt * 16 + n;
            const short8 kf0 = *(const short8*)&Ks[cur][j * 64 + (((0 + g) ^ (j & 7)) << 3)];
            const short8 kf1 = *(const short8*)&Ks[cur][j * 64 + (((4 + g) ^ (j & 7)) << 3)];
            floatx4 a = (floatx4){0.f, 0.f, 0.f, 0.f};
            a = __builtin_amdgcn_mfma_f32_16x16x32_bf16(qa0, kf0, a, 0, 0, 0);
            a = __builtin_amdgcn_mfma_f32_16x16x32_bf16(qa1, kf1, a, 0, 0, 0);
            S[nt] = a;
        }

        // ---- online softmax ------------------------------------------------
        float mx[4];
        #pragma unroll
        for (int r = 0; r < 4; ++r) mx[r] = -1e30f;
        #pragma unroll
        for (int nt = 0; nt < 2; ++nt)
            #pragma unroll
            for (int r = 0; r < 4; ++r)
                mx[r] = fmaxf(mx[r], S[nt][r]);
        #pragma unroll
        for (int off = 8; off >= 1; off >>= 1)
            #pragma unroll
            for (int r = 0; r < 4; ++r)
                mx[r] = fmaxf(mx[r], __shfl_xor(mx[r], off, 64));

        float alpha[4], ps[4];
        #pragma unroll
        for (int r = 0; r < 4; ++r) {
            const float Mn = fmaxf(m_i[r], mx[r]);
            alpha[r] = __expf(m_i[r] - Mn);
            m_i[r]   = Mn;
            ps[r]    = 0.f;
        }
        float p[2][4];
        #pragma unroll
        for (int nt = 0; nt < 2; ++nt)
            #pragma unroll
            for (int r = 0; r < 4; ++r) {
                p[nt][r] = __expf(S[nt][r] - m_i[r]);
                ps[r] += p[nt][r];
            }
        #pragma unroll
        for (int off = 8; off >= 1; off >>= 1)
            #pragma unroll
            for (int r = 0; r < 4; ++r)
                ps[r] += __shfl_xor(ps[r], off, 64);
        #pragma unroll
        for (int r = 0; r < 4; ++r) l_i[r] = l_i[r] * alpha[r] + ps[r];
        #pragma unroll
        for (int ht = 0; ht < 4; ++ht)
            #pragma unroll
            for (int r = 0; r < 4; ++r) Oa[ht][r] *= alpha[r];

        // ---- P: C-layout -> LDS -> A-layout (per-wave, no barrier needed) --
        #pragma unroll
        for (int nt = 0; nt < 2; ++nt)
            #pragma unroll
            for (int r = 0; r < 4; ++r)
                Pw[wave][(g * 4 + r) * 72 + nt * 16 + n] = f2bf(p[nt][r]);
        const short8 pa = *(const short8*)&Pw[wave][n * 72 + g * 8];

        // ---- PV: O[16 q][64 h] += P[16 x 32] @ V[32 x 64] ------------------
        #pragma unroll
        for (int ht = 0; ht < 4; ++ht) {
            const int h = ht * 16 + n;
            const short8 vf = *(const short8*)((const char*)&Vt[cur][0] + h * 128 +
                                               ((((ks << 2) + g) ^ (h & 7)) << 4));
            Oa[ht] = __builtin_amdgcn_mfma_f32_16x16x32_bf16(pa, vf, Oa[ht], 0, 0, 0);
        }

        // ---- write next tile into the other buffer -------------------------
        if (t + 1 < SS / 64) {
            const int nx = cur ^ 1;
            *(short8*)&Ks[nx][jK0 * 64 + ((cs ^ (jK0 & 7)) << 3)] = kr0;
            *(short8*)&Ks[nx][jK1 * 64 + ((cs ^ (jK1 & 7)) << 3)] = kr1;
            const u16* a0 = (const u16*)&vr0; const u16* a1 = (const u16*)&vr1;
            const u16* a2 = (const u16*)&vr2; const u16* a3 = (const u16*)&vr3;
            #pragma unroll
            for (int i = 0; i < 4; ++i) {
                const int h = hV + i;
                ushort4 w; w.x = a0[i]; w.y = a1[i]; w.z = a2[i]; w.w = a3[i];
                *(ushort4*)((char*)&Vt[nx][0] + h * 128 + (((jV >> 3) ^ (h & 7)) << 4) + ((jV & 4) << 1)) = w;
            }
        }
        __syncthreads();
    }

    // ---- combine the two key-splits via LDS (reuse Ks) ----------------------
    float* Cb = (float*)&Ks[0][0];          // [wq][16][68]
    float* Cm = Cb + 2 * 16 * 68;           // [wq][16]
    float* Cl = Cm + 32;
    if (ks == 1) {
        #pragma unroll
        for (int ht = 0; ht < 4; ++ht)
            #pragma unroll
            for (int r = 0; r < 4; ++r)
                Cb[(wq * 16 + g * 4 + r) * 68 + ht * 16 + n] = Oa[ht][r];
        if (n == 0)
            #pragma unroll
            for (int r = 0; r < 4; ++r) {
                Cm[wq * 16 + g * 4 + r] = m_i[r];
                Cl[wq * 16 + g * 4 + r] = l_i[r];
            }
    }
    __syncthreads();
    if (ks == 0) {
        float a0v[4], a1v[4], linv[4];
        #pragma unroll
        for (int r = 0; r < 4; ++r) {
            const int m = g * 4 + r;
            const float m1 = Cm[wq * 16 + m], l1 = Cl[wq * 16 + m];
            const float M  = fmaxf(m_i[r], m1);
            const float e0 = __expf(m_i[r] - M), e1 = __expf(m1 - M);
            a0v[r] = e0; a1v[r] = e1;
            linv[r] = 1.f / (l_i[r] * e0 + l1 * e1);
        }
        #pragma unroll
        for (int ht = 0; ht < 4; ++ht)
            #pragma unroll
            for (int r = 0; r < 4; ++r) {
                const float o1 = Cb[(wq * 16 + g * 4 + r) * 68 + ht * 16 + n];
                const float v  = (Oa[ht][r] * a0v[r] + o1 * a1v[r]) * linv[r];
                out[((size_t)b * SS + q0 + wq * 16 + g * 4 + r) * HH + ht * 16 + n] = v;
            }
    }
}

// ---------------------------------------------------------------------------
extern "C" void kernel_launch(void* const* d_in, const int* in_sizes, int n_in,
                              void* d_out, int out_size, void* d_ws, size_t ws_size,
                              hipStream_t stream) {
    const float* query = (const float*)d_in[0];
    const float* key   = (const float*)d_in[1];
    const float* value = (const float*)d_in[2];
    const float* Wq    = (const float*)d_in[3];
    const float* bq    = (const float*)d_in[4];
    const float* Wk    = (const float*)d_in[5];
    const float* bk    = (const float*)d_in[6];
    const float* Wv    = (const float*)d_in[7];
    const float* bv    = (const float*)d_in[8];
    float* out = (float*)d_out;

    u16* qp = (u16*)d_ws;                        // 16384 x 64 bf16 each
    u16* kp = qp + (size_t)MM * HH;
    u16* vp = kp + (size_t)MM * HH;
    u16* Wp = vp + (size_t)MM * HH;              // 3 * 256 KB packed W frags

    dim3 wgrid(EE / 64, 3);
    pack_w<<<wgrid, 512, 0, stream>>>(Wq, Wk, Wv, Wp);

    dim3 pgrid(MM / 64, 3);
    proj_mfma<<<pgrid, 256, 0, stream>>>(query, key, value,
                                         Wp,
                                         bq, bk, bv,
                                         qp, kp, vp);

    dim3 agrid(SS / 32, BB);
    flash_mfma<<<agrid, 256, 0, stream>>>(qp, kp, vp, out);
}